// Round 7
// baseline (733.161 us; speedup 1.0000x reference)
//
#include <hip/hip_runtime.h>
#include <hip/hip_fp16.h>

#define NB 4
#define NR 256
#define NC 256
#define NCOIL 32
#define NSEG 4
#define NPOL 2
#define OD 276
#define OFF 10
#define NCC 16          // partial chunks = NCOIL/2 (2 coils per stageC block)

typedef float2 c32;

__device__ __forceinline__ c32 cmul(c32 a, c32 b){
  return make_float2(a.x*b.x - a.y*b.y, a.x*b.y + a.y*b.x);
}
__device__ __forceinline__ c32 cmulj(c32 a, c32 b){ // a * conj(b)
  return make_float2(a.x*b.x + a.y*b.y, a.y*b.x - a.x*b.y);
}

// ---------------------------------------------------------------------------
// Shuffle-based 256-pt FFT: 256 = 4 (regs) x 64 (lanes).
// Forward: input  reg i, lane u = x[64i+u] (natural);
//          output reg j, lane u = X[4*rev6(u) + j]   (scrambled order pi).
// Inverse: input  reg j, lane u = Y[4*rev6(u) + j];
//          output reg i, lane u = y[64i+u] (natural), unnormalized sum.
// pi(s) = 4*rev6(s&63) + (s>>6);  pi_inv(k) = ((k&3)<<6) | rev6(k>>2).
// All twiddles are per-lane constants, hoisted once per kernel (no LDS).

struct Twid { c32 f4[3]; c32 f[6]; };

__device__ __forceinline__ void make_tw(int u, Twid& T){
  float sn, cs;
  sincosf(0.024543692606170260f * (float)u, &sn, &cs);   // 2*pi*u/256
  T.f4[0] = make_float2(cs, -sn);                         // W256^u
  T.f4[1] = cmul(T.f4[0], T.f4[0]);                       // W256^2u
  T.f4[2] = cmul(T.f4[1], T.f4[0]);                       // W256^3u
  #pragma unroll
  for (int s = 0; s < 6; ++s){
    const int d = 32 >> s;
    int e = (u & d) ? (u & (d-1)) : 0;                    // ->(1,0) on even role
    float ang = 3.14159265358979323846f * (float)e / (float)d;
    sincosf(ang, &sn, &cs);
    T.f[s] = make_float2(cs, -sn);                        // W64^{e*32/d}
  }
}

__device__ __forceinline__ c32 shflx(c32 v, int m){
  return make_float2(__shfl_xor(v.x, m, 64), __shfl_xor(v.y, m, 64));
}

__device__ __forceinline__ void fft256_fwd(c32* x, const Twid& T, int u){
  // radix-4 over registers (w4 = -i), then twiddle W256^{u*j}
  c32 a  = make_float2(x[0].x+x[2].x, x[0].y+x[2].y);
  c32 b  = make_float2(x[0].x-x[2].x, x[0].y-x[2].y);
  c32 c  = make_float2(x[1].x+x[3].x, x[1].y+x[3].y);
  c32 dd = make_float2(x[1].x-x[3].x, x[1].y-x[3].y);
  x[0] = make_float2(a.x+c.x, a.y+c.y);
  x[2] = cmul(make_float2(a.x-c.x, a.y-c.y), T.f4[1]);
  x[1] = cmul(make_float2(b.x+dd.y, b.y-dd.x), T.f4[0]);   // b - i*dd
  x[3] = cmul(make_float2(b.x-dd.y, b.y+dd.x), T.f4[2]);   // b + i*dd
  // 6 radix-2 DIF stages across lanes, d = 32..1; output bit-reversed
  #pragma unroll
  for (int s = 0; s < 6; ++s){
    const int d = 32 >> s;
    #pragma unroll
    for (int j = 0; j < 4; ++j){
      c32 o = shflx(x[j], d);
      c32 t;
      if (u & d){ t.x = o.x - x[j].x; t.y = o.y - x[j].y; }
      else      { t.x = x[j].x + o.x; t.y = x[j].y + o.y; }
      x[j] = cmul(t, T.f[s]);                 // f[s]=(1,0) on even role
    }
  }
}

__device__ __forceinline__ void fft256_inv(c32* x, const Twid& T, int u){
  // 6 radix-2 DIT stages, d = 1..32, conj twiddles (twiddle own value first)
  #pragma unroll
  for (int s = 0; s < 6; ++s){
    const int d = 1 << s;
    #pragma unroll
    for (int j = 0; j < 4; ++j){
      c32 vt = cmulj(x[j], T.f[5-s]);
      c32 o = shflx(vt, d);
      if (u & d){ x[j].x = o.x - vt.x; x[j].y = o.y - vt.y; }
      else      { x[j].x = vt.x + o.x; x[j].y = vt.y + o.y; }
    }
  }
  // conj twiddle then inverse radix-4 over registers (w4^-1 = +i)
  x[1] = cmulj(x[1], T.f4[0]);
  x[2] = cmulj(x[2], T.f4[1]);
  x[3] = cmulj(x[3], T.f4[2]);
  c32 a  = make_float2(x[0].x+x[2].x, x[0].y+x[2].y);
  c32 b  = make_float2(x[0].x-x[2].x, x[0].y-x[2].y);
  c32 c  = make_float2(x[1].x+x[3].x, x[1].y+x[3].y);
  c32 dd = make_float2(x[1].x-x[3].x, x[1].y-x[3].y);
  x[0] = make_float2(a.x+c.x, a.y+c.y);
  x[2] = make_float2(a.x-c.x, a.y-c.y);
  x[1] = make_float2(b.x-dd.y, b.y+dd.x);    // b + i*dd
  x[3] = make_float2(b.x+dd.y, b.y-dd.x);    // b - i*dd
}

__device__ __forceinline__ int pinv(int k){  // pi^{-1} on 0..255
  int r6 = (int)(__brev((unsigned)(k >> 2)) >> 26);
  return ((k & 3) << 6) | r6;
}

// ---------------------------------------------------------------------------
__global__ __launch_bounds__(256) void zero_kernel(float* __restrict__ out, int n){
  int i = blockIdx.x*256 + threadIdx.x;
  if (i < n) out[i] = 0.0f;
}

// ---------------------------------------------------------------------------
// pack_common: img_t natural; w_t natural; m_t SCRAMBLED both dims:
// m_t[bl][ps][pinv(c)][pinv(r)] = mask(kr=r, kc=c).
__global__ __launch_bounds__(256) void pack_common_kernel(
    int b0,
    const float* __restrict__ x_re, const float* __restrict__ x_im,
    const float* __restrict__ wm_re, const float* __restrict__ wm_im,
    const float* __restrict__ mask,
    c32* __restrict__ img_t, c32* __restrict__ w_t, float* __restrict__ m_t)
{
  int r = blockIdx.x & (NR-1);
  int bl = blockIdx.x >> 8;
  int b = b0 + bl;
  int c = threadIdx.x;
  const size_t PL = (size_t)NR*NC;
  float sc = (((r + c) & 1) ? -1.0f : 1.0f) * (1.0f/256.0f);
  size_t xrow = (((size_t)b*OD) + (r+OFF))*OD + (c+OFF);
  #pragma unroll
  for (int pol = 0; pol < NPOL; ++pol){
    size_t xi = xrow*NPOL + pol;
    img_t[((size_t)(bl*NPOL+pol))*PL + (size_t)r*NC + c] =
        make_float2(x_re[xi]*sc, x_im[xi]*sc);
  }
  int rs = pinv(r), cs = pinv(c);
  size_t wbase = (((size_t)b*NR + r)*NC + c)*(NPOL*NSEG);
  const float4* wre4 = (const float4*)&wm_re[wbase];
  const float4* wim4 = (const float4*)&wm_im[wbase];
  const float4* mk4  = (const float4*)&mask[wbase];
  #pragma unroll
  for (int pol = 0; pol < NPOL; ++pol){
    float4 re = wre4[pol], im = wim4[pol], mk = mk4[pol];
    float rr[4] = {re.x, re.y, re.z, re.w};
    float ii[4] = {im.x, im.y, im.z, im.w};
    float mm[4] = {mk.x, mk.y, mk.z, mk.w};
    #pragma unroll
    for (int seg = 0; seg < NSEG; ++seg){
      int ps = bl*(NPOL*NSEG) + pol*NSEG + seg;
      w_t[(size_t)ps*PL + (size_t)r*NC + c] = make_float2(rr[seg], ii[seg]);
      m_t[(size_t)ps*PL + (size_t)cs*NR + rs] = mm[seg];
    }
  }
}

// pack_csm: batch b, all coils: c_t[cl][r][c].  grid: NR blocks of 256
__global__ __launch_bounds__(256) void pack_csm_kernel(
    int b,
    const float* __restrict__ csm_re, const float* __restrict__ csm_im,
    c32* __restrict__ c_t)
{
  int r = blockIdx.x;
  int c = threadIdx.x;
  const size_t PL = (size_t)NR*NC;
  size_t base = (((size_t)b*NR + r)*NC + c)*NCOIL;
  c32* cp = c_t + (size_t)r*NC + c;
  for (int cl = 0; cl < NCOIL; cl += 4){
    float4 re = *(const float4*)&csm_re[base + cl];
    float4 im = *(const float4*)&csm_im[base + cl];
    cp[(size_t)(cl+0)*PL] = make_float2(re.x, im.x);
    cp[(size_t)(cl+1)*PL] = make_float2(re.y, im.y);
    cp[(size_t)(cl+2)*PL] = make_float2(re.z, im.z);
    cp[(size_t)(cl+3)*PL] = make_float2(re.w, im.w);
  }
}

// ---------------------------------------------------------------------------
// stage A: g = img*w*csm, row fwd-FFT (scrambled out), write T1[p][cslot][r]
// grid: CH*NPOL*NSEG*16 blocks of 256 (4 waves, 4 rows each)
__global__ __launch_bounds__(256) void stageA_kernel(
    const c32* __restrict__ img_t, const c32* __restrict__ w_t,
    const c32* __restrict__ c_t, __half2* __restrict__ T1)
{
  __shared__ __half2 tile[NC*17];
  int tid = threadIdx.x;
  int u = tid & 63, w = tid >> 6;
  Twid T; make_tw(u, T);
  int bid = blockIdx.x;
  int p  = bid >> 4;           // ((cl*NPOL)+pol)*NSEG+seg
  int rt = bid & 15;
  int seg = p & 3, pol = (p>>2) & 1, cl = p >> 3;

  #pragma unroll 1
  for (int ri = 0; ri < 4; ++ri){
    int rl = w*4 + ri;
    int r = rt*16 + rl;
    const c32* ir = img_t + ((size_t)pol*NR + r)*NC;
    const c32* wr = w_t  + ((size_t)(pol*NSEG+seg)*NR + r)*NC;
    const c32* cr = c_t  + ((size_t)cl*NR + r)*NC;
    c32 x[4];
    #pragma unroll
    for (int i = 0; i < 4; ++i){
      int c = u + 64*i;
      x[i] = cmul(cmul(ir[c], wr[c]), cr[c]);
    }
    fft256_fwd(x, T, u);
    #pragma unroll
    for (int t = 0; t < 4; ++t){
      int c = u + 64*t;                      // slot index
      tile[c*17 + rl] = __floats2half2_rn(x[t].x, x[t].y);
    }
  }
  __syncthreads();
  __half2* tp = T1 + (size_t)p*(NR*NC);
  int r0 = rt*16;
  #pragma unroll
  for (int cb = 0; cb < 16; ++cb){
    int cc = w*64 + cb*4 + (u >> 4);
    int rl = u & 15;
    tp[cc*NR + r0 + rl] = tile[cc*17 + rl];
  }
}

// ---------------------------------------------------------------------------
// stage B: per column-slot: col fwd-FFT per seg (scrambled out), K=sum(mask*X)
// (mask pre-scrambled), per seg' re-mask, col inv-FFT (natural out), *(1/256),
// transpose via [16][256] LDS tile, write T2[p][r][cslot] row-major.
// grid: CH*NPOL*16 blocks of 256 (4 waves, 4 columns per wave)
__global__ __launch_bounds__(256) void stageB_kernel(
    const __half2* __restrict__ T1, const float* __restrict__ m_t,
    __half2* __restrict__ T2)
{
  __shared__ __half2 tile[16][256];
  int tid = threadIdx.x, u = tid & 63, w = tid >> 6;
  Twid T; make_tw(u, T);
  int bid = blockIdx.x;
  int ct = bid & 15;           // column panel
  int g  = bid >> 4;           // cl*NPOL + pol
  int pol = g & 1;
  int c0 = ct*16;
  const size_t PL = (size_t)NR*NC;

  c32 K[4][4];
  #pragma unroll
  for (int j = 0; j < 4; ++j)
    #pragma unroll
    for (int t = 0; t < 4; ++t) K[j][t] = make_float2(0.f, 0.f);

  // phase 1: forward column FFTs, K = sum_seg mask*FFT(col)
  #pragma unroll
  for (int j = 0; j < 4; ++j){
    int col = c0 + w*4 + j;
    #pragma unroll 1
    for (int seg = 0; seg < NSEG; ++seg){
      const __half2* tp = T1 + ((size_t)(g*NSEG+seg))*PL + (size_t)col*NR;
      const float*  mp = m_t + ((size_t)(pol*NSEG+seg))*PL + (size_t)col*NR;
      c32 x[4];
      float mv[4];
      #pragma unroll
      for (int i = 0; i < 4; ++i){
        x[i]  = __half22float2(tp[u + 64*i]);
        mv[i] = mp[u + 64*i];
      }
      fft256_fwd(x, T, u);
      #pragma unroll
      for (int t = 0; t < 4; ++t){
        K[j][t].x += mv[t]*x[t].x;
        K[j][t].y += mv[t]*x[t].y;
      }
    }
  }
  // phase 2: per seg' re-mask, inverse col FFT, transpose, row-major store
  #pragma unroll 1
  for (int seg = 0; seg < NSEG; ++seg){
    #pragma unroll
    for (int j = 0; j < 4; ++j){
      int col = c0 + w*4 + j;
      const float* mp = m_t + ((size_t)(pol*NSEG+seg))*PL + (size_t)col*NR;
      c32 x[4];
      #pragma unroll
      for (int t = 0; t < 4; ++t){
        float mv = mp[u + 64*t];
        x[t] = make_float2(K[j][t].x*mv, K[j][t].y*mv);
      }
      fft256_inv(x, T, u);
      #pragma unroll
      for (int t = 0; t < 4; ++t)
        tile[w*4+j][u + 64*t] = __floats2half2_rn(x[t].x*(1.0f/256.0f),
                                                  x[t].y*(1.0f/256.0f));
    }
    __syncthreads();
    {
      int r = tid;
      unsigned pk[16];
      #pragma unroll
      for (int k = 0; k < 16; ++k){
        __half2 h = tile[k][r];
        pk[k] = *(unsigned*)&h;
      }
      uint4* dst = (uint4*)(T2 + ((size_t)(g*NSEG+seg))*PL + (size_t)r*NC + c0);
      dst[0] = make_uint4(pk[0],  pk[1],  pk[2],  pk[3]);
      dst[1] = make_uint4(pk[4],  pk[5],  pk[6],  pk[7]);
      dst[2] = make_uint4(pk[8],  pk[9],  pk[10], pk[11]);
      dst[3] = make_uint4(pk[12], pk[13], pk[14], pk[15]);
    }
    __syncthreads();
  }
}

// ---------------------------------------------------------------------------
// stage C (partial): row inv-FFT from T2 (scrambled slots -> natural c),
// * conj(w)*conj(csm), accumulate 2 coils x 4 segs, write fp16 partial.
// NO LDS at all.  grid: (CH/2)*NPOL*64 blocks of 256 (4 waves, 1 row each)
__global__ __launch_bounds__(256) void stageC_part_kernel(
    const __half2* __restrict__ T2, const c32* __restrict__ w_t,
    const c32* __restrict__ c_t, __half2* __restrict__ part, int ch0)
{
  int tid = threadIdx.x, u = tid & 63, w = tid >> 6;
  Twid T; make_tw(u, T);
  int bid = blockIdx.x;
  int rq = bid & 63, pol = (bid>>6) & 1, ch = bid >> 7;   // local coil pair
  int r = rq*4 + w;
  const size_t PL = (size_t)NR*NC;

  c32 acc[4];
  #pragma unroll
  for (int t = 0; t < 4; ++t) acc[t] = make_float2(0.f, 0.f);

  __half2 v[4];
  {
    const __half2* rp = T2 + ((size_t)((ch*2*NPOL+pol)*NSEG))*PL + (size_t)r*NC;
    #pragma unroll
    for (int i = 0; i < 4; ++i) v[i] = rp[u + 64*i];
  }
  #pragma unroll 1
  for (int pl = 0; pl < 2*NSEG; ++pl){
    int cl = ch*2 + (pl>>2), seg = pl & 3;
    c32 x[4];
    #pragma unroll
    for (int i = 0; i < 4; ++i) x[i] = __half22float2(v[i]);
    if (pl < 2*NSEG-1){
      int cl2 = ch*2 + ((pl+1)>>2), seg2 = (pl+1) & 3;
      const __half2* rp = T2 + ((size_t)((cl2*NPOL+pol)*NSEG+seg2))*PL + (size_t)r*NC;
      #pragma unroll
      for (int i = 0; i < 4; ++i) v[i] = rp[u + 64*i];
    }
    fft256_inv(x, T, u);
    const c32* wr = w_t + ((size_t)(pol*NSEG+seg)*NR + r)*NC;
    const c32* cr = c_t + ((size_t)cl*NR + r)*NC;
    #pragma unroll
    for (int t = 0; t < 4; ++t){
      int cp = u + 64*t;                    // natural column
      c32 vv = cmulj(x[t], wr[cp]);
      vv = cmulj(vv, cr[cp]);
      acc[t].x += vv.x;
      acc[t].y += vv.y;
    }
  }
  __half2* pp = part + ((size_t)((ch0+ch)*NPOL+pol))*PL + (size_t)r*NC;
  #pragma unroll
  for (int t = 0; t < 4; ++t)
    pp[u + 64*t] = __floats2half2_rn(acc[t].x, acc[t].y);
}

// reduceC: out interior = sign * sum over 16 chunks of partial. Plain stores.
// grid: NR blocks of 256 (thread = c, block = r)
__global__ __launch_bounds__(256) void reduceC_kernel(
    int b, const __half2* __restrict__ part, float* __restrict__ out)
{
  int r = blockIdx.x, c = threadIdx.x;
  const size_t PL = (size_t)NR*NC;
  float2 s[NPOL];
  #pragma unroll
  for (int pol = 0; pol < NPOL; ++pol) s[pol] = make_float2(0.f, 0.f);
  #pragma unroll 4
  for (int ch = 0; ch < NCC; ++ch){
    #pragma unroll
    for (int pol = 0; pol < NPOL; ++pol){
      float2 f = __half22float2(part[((size_t)(ch*NPOL+pol))*PL + (size_t)r*NC + c]);
      s[pol].x += f.x; s[pol].y += f.y;
    }
  }
  float sgn = ((r + c) & 1) ? -1.0f : 1.0f;
  float4 o = make_float4(sgn*s[0].x, sgn*s[0].y, sgn*s[1].x, sgn*s[1].y);
  size_t oidx = (((size_t)b*OD + (r+OFF))*OD + (c+OFF));   // float4 units
  ((float4*)out)[oidx] = o;
}

// ---------------------------------------------------------------------------
extern "C" void kernel_launch(void* const* d_in, const int* in_sizes, int n_in,
                              void* d_out, int out_size, void* d_ws, size_t ws_size,
                              hipStream_t stream)
{
  (void)in_sizes; (void)n_in;
  const float* x_re   = (const float*)d_in[0];
  const float* x_im   = (const float*)d_in[1];
  const float* csm_re = (const float*)d_in[2];
  const float* csm_im = (const float*)d_in[3];
  const float* wm_re  = (const float*)d_in[4];
  const float* wm_im  = (const float*)d_in[5];
  const float* mask   = (const float*)d_in[6];

  const size_t PL = (size_t)NR*NC;
  const size_t imgB1 = (size_t)NPOL*PL*sizeof(c32);           // 1 MiB / batch
  const size_t wB1   = (size_t)NPOL*NSEG*PL*sizeof(c32);      // 4 MiB / batch
  const size_t mB1   = (size_t)NPOL*NSEG*PL*sizeof(float);    // 2 MiB / batch
  const size_t csmB1 = (size_t)NCOIL*PL*sizeof(c32);          // 16 MiB / batch
  const size_t partB = (size_t)NCC*NPOL*PL*4;                 // 32 MiB fp16
  const size_t coilB = (size_t)NPOL*NSEG*PL*4;                // 2 MiB fp16 / coil

  const size_t fixed = NB*(imgB1 + wB1 + mB1) + csmB1 + partB; // 76 MiB

  // coil chunk: T1 + T2 = CH * 4 MiB extra.  CH=16 needs 140 MiB (known fit).
  int CH = 32;
  while (CH > 4){
    if (fixed + (size_t)CH*2*coilB <= ws_size) break;
    CH >>= 1;
  }

  char* ws = (char*)d_ws;
  c32* img_t = (c32*)ws;
  c32* w_t   = (c32*)(ws + NB*imgB1);
  float* m_t = (float*)(ws + NB*(imgB1 + wB1));
  c32* c_t   = (c32*)(ws + NB*(imgB1 + wB1 + mB1));
  __half2* part = (__half2*)(ws + NB*(imgB1 + wB1 + mB1) + csmB1);
  __half2* T1 = (__half2*)(ws + fixed);
  __half2* T2 = (__half2*)(ws + fixed + (size_t)CH*coilB);

  float* out = (float*)d_out;
  zero_kernel<<<(out_size + 255)/256, 256, 0, stream>>>(out, out_size);

  pack_common_kernel<<<NB*NR, 256, 0, stream>>>(0, x_re, x_im, wm_re, wm_im,
                                                mask, img_t, w_t, m_t);
  for (int b = 0; b < NB; ++b){
    c32* img_b = img_t + (size_t)b*NPOL*PL;
    c32* w_b   = w_t   + (size_t)b*NPOL*NSEG*PL;
    float* m_b = m_t   + (size_t)b*NPOL*NSEG*PL;
    pack_csm_kernel<<<NR, 256, 0, stream>>>(b, csm_re, csm_im, c_t);
    for (int c0 = 0; c0 < NCOIL; c0 += CH){
      c32* c_b = c_t + (size_t)c0*PL;
      stageA_kernel<<<CH*NPOL*NSEG*16, 256, 0, stream>>>(img_b, w_b, c_b, T1);
      stageB_kernel<<<CH*NPOL*16, 256, 0, stream>>>(T1, m_b, T2);
      stageC_part_kernel<<<(CH/2)*NPOL*64, 256, 0, stream>>>(T2, w_b, c_b,
                                                             part, c0/2);
    }
    reduceC_kernel<<<NR, 256, 0, stream>>>(b, part, out);
  }
}

// Round 8
// 687.724 us; speedup vs baseline: 1.0661x; 1.0661x over previous
//
#include <hip/hip_runtime.h>
#include <hip/hip_fp16.h>

#define NB 4
#define NR 256
#define NC 256
#define NCOIL 32
#define NSEG 4
#define NPOL 2
#define OD 276
#define OFF 10
#define NCC 16          // partial chunks = NCOIL/2 (2 coils per stageC block)

typedef float2 c32;

__device__ __forceinline__ c32 cmul(c32 a, c32 b){
  return make_float2(a.x*b.x - a.y*b.y, a.x*b.y + a.y*b.x);
}
__device__ __forceinline__ c32 cmulj(c32 a, c32 b){ // a * conj(b)
  return make_float2(a.x*b.x + a.y*b.y, a.y*b.x - a.x*b.y);
}
__device__ __forceinline__ int pd(int a){ return a + (a >> 4); }
__device__ __forceinline__ void wsync(){ __builtin_amdgcn_wave_barrier(); }

// p-order: p(r) = 4*(r&63) + (r>>6);  r(p) = 64*(p&3) + (p>>2)
__device__ __forceinline__ int pord(int r){ return 4*(r & 63) + (r >> 6); }

// Per-lane register twiddles for the 4 Stockham stages (replaces LDS table:
// exponent e1 = u & ~(m-1) is a per-lane constant per stage).
struct TW { c32 t1[4]; c32 t2[4]; c32 t3[4]; };
__device__ __forceinline__ void mk_tw(int u, TW& T){
  #pragma unroll
  for (int s = 0; s < 4; ++s){
    int e = u & ~((1 << (2*s)) - 1);
    float a = -0.0245436926061703f * (float)e;   // -2*pi*e/256
    float sn, cs; sincosf(a, &sn, &cs);
    c32 w1 = make_float2(cs, sn);                // W256^e (fwd sign)
    T.t1[s] = w1;
    T.t2[s] = cmul(w1, w1);
    T.t3[s] = cmul(T.t2[s], w1);
  }
}

// 256-pt radix-4 Stockham, one wave, 4 c32/lane, wave-private LDS b0/b1.
// xin/xout natural order: x[u+64*i].  DIR=+1 fwd, DIR=-1 unnormalized inverse.
template<int DIR>
__device__ __forceinline__ void fft256(c32* x, c32* b0, c32* b1,
                                       const TW& T, int u){
  #pragma unroll
  for (int s = 0; s < 4; ++s){
    const int m = 1 << (2*s);
    c32 a0, a1, a2, a3;
    if (s == 0){ a0 = x[0]; a1 = x[1]; a2 = x[2]; a3 = x[3]; }
    else {
      const c32* src = ((s & 1) ? b0 : b1);   // s=1:b0, s=2:b1, s=3:b0
      a0 = src[pd(u)]; a1 = src[pd(u+64)]; a2 = src[pd(u+128)]; a3 = src[pd(u+192)];
    }
    c32 s0 = make_float2(a0.x+a2.x, a0.y+a2.y);
    c32 d0 = make_float2(a0.x-a2.x, a0.y-a2.y);
    c32 s1 = make_float2(a1.x+a3.x, a1.y+a3.y);
    c32 d1 = make_float2(a1.x-a3.x, a1.y-a3.y);
    c32 X0 = make_float2(s0.x+s1.x, s0.y+s1.y);
    c32 X2 = make_float2(s0.x-s1.x, s0.y-s1.y);
    c32 X1, X3;
    if (DIR > 0){
      X1 = make_float2(d0.x + d1.y, d0.y - d1.x);  // d0 - i*d1
      X3 = make_float2(d0.x - d1.y, d0.y + d1.x);  // d0 + i*d1
    } else {
      X1 = make_float2(d0.x - d1.y, d0.y + d1.x);
      X3 = make_float2(d0.x + d1.y, d0.y - d1.x);
    }
    c32 w1 = T.t1[s], w2 = T.t2[s], w3 = T.t3[s];
    if (DIR < 0){ w1.y = -w1.y; w2.y = -w2.y; w3.y = -w3.y; }
    X1 = cmul(X1, w1); X2 = cmul(X2, w2); X3 = cmul(X3, w3);
    if (s == 3){
      x[0] = X0; x[1] = X1; x[2] = X2; x[3] = X3;
    } else {
      c32* dst = ((s & 1) ? b1 : b0);         // s=0:b0, s=1:b1, s=2:b0
      int j = u >> (2*s);
      int k = u & (m-1);
      int base = k + 4*m*j;
      dst[pd(base)]      = X0;
      dst[pd(base+m)]    = X1;
      dst[pd(base+2*m)]  = X2;
      dst[pd(base+3*m)]  = X3;
    }
    wsync();
  }
}

// ---------------------------------------------------------------------------
__global__ __launch_bounds__(256) void zero_kernel(float* __restrict__ out, int n){
  int i = blockIdx.x*256 + threadIdx.x;
  if (i < n) out[i] = 0.0f;
}

// ---------------------------------------------------------------------------
// pack_common: img_t[bl][pol][r][c] natural; w_t[bl][ps][r][c] natural;
// m_t[bl][ps][c][p(r)] fp16 (p-order along r).  grid: NB*NR blocks of 256.
__global__ __launch_bounds__(256) void pack_common_kernel(
    const float* __restrict__ x_re, const float* __restrict__ x_im,
    const float* __restrict__ wm_re, const float* __restrict__ wm_im,
    const float* __restrict__ mask,
    c32* __restrict__ img_t, c32* __restrict__ w_t, __half* __restrict__ m_t)
{
  int r = blockIdx.x & (NR-1);
  int bl = blockIdx.x >> 8;
  int c = threadIdx.x;
  const size_t PL = (size_t)NR*NC;
  float sc = (((r + c) & 1) ? -1.0f : 1.0f) * (1.0f/256.0f);
  size_t xrow = (((size_t)bl*OD) + (r+OFF))*OD + (c+OFF);
  #pragma unroll
  for (int pol = 0; pol < NPOL; ++pol){
    size_t xi = xrow*NPOL + pol;
    img_t[((size_t)(bl*NPOL+pol))*PL + (size_t)r*NC + c] =
        make_float2(x_re[xi]*sc, x_im[xi]*sc);
  }
  int pr = pord(r);
  size_t wbase = (((size_t)bl*NR + r)*NC + c)*(NPOL*NSEG);
  const float4* wre4 = (const float4*)&wm_re[wbase];
  const float4* wim4 = (const float4*)&wm_im[wbase];
  const float4* mk4  = (const float4*)&mask[wbase];
  #pragma unroll
  for (int pol = 0; pol < NPOL; ++pol){
    float4 re = wre4[pol], im = wim4[pol], mk = mk4[pol];
    float rr[4] = {re.x, re.y, re.z, re.w};
    float ii[4] = {im.x, im.y, im.z, im.w};
    float mm[4] = {mk.x, mk.y, mk.z, mk.w};
    #pragma unroll
    for (int seg = 0; seg < NSEG; ++seg){
      int ps = bl*(NPOL*NSEG) + pol*NSEG + seg;
      w_t[(size_t)ps*PL + (size_t)r*NC + c] = make_float2(rr[seg], ii[seg]);
      m_t[((size_t)ps*NC + c)*NR + pr] = __float2half(mm[seg]);
    }
  }
}

// pack_csm: batch b, all coils, natural: c_t[cl][r][c].  grid: NR blocks.
__global__ __launch_bounds__(256) void pack_csm_kernel(
    int b,
    const float* __restrict__ csm_re, const float* __restrict__ csm_im,
    c32* __restrict__ c_t)
{
  int r = blockIdx.x;
  int c = threadIdx.x;
  const size_t PL = (size_t)NR*NC;
  size_t base = (((size_t)b*NR + r)*NC + c)*NCOIL;
  c32* cp = c_t + (size_t)r*NC + c;
  for (int cl = 0; cl < NCOIL; cl += 4){
    float4 re = *(const float4*)&csm_re[base + cl];
    float4 im = *(const float4*)&csm_im[base + cl];
    cp[(size_t)(cl+0)*PL] = make_float2(re.x, im.x);
    cp[(size_t)(cl+1)*PL] = make_float2(re.y, im.y);
    cp[(size_t)(cl+2)*PL] = make_float2(re.z, im.z);
    cp[(size_t)(cl+3)*PL] = make_float2(re.w, im.w);
  }
}

// ---------------------------------------------------------------------------
// stage A: row FFT of img*w*csm; block owns rows {4rt+w+64m}; writes
// T1[p][kc][p-order r] fp16, full 64B lines per (block, kc).
// grid: CH*NPOL*NSEG*16 blocks of 256.
__global__ __launch_bounds__(256) void stageA_kernel(
    const c32* __restrict__ img_t, const c32* __restrict__ w_t,
    const c32* __restrict__ c_t, __half2* __restrict__ T1)
{
  __shared__ c32 fbuf[4][2][272];
  __shared__ __half2 tile[NC*17];
  int tid = threadIdx.x;
  int u = tid & 63, w = tid >> 6;
  TW T; mk_tw(u, T);
  int bid = blockIdx.x;
  int p  = bid >> 4;           // ((cl*NPOL)+pol)*NSEG+seg
  int rt = bid & 15;
  int seg = p & 3, pol = (p>>2) & 1, cl = p >> 3;

  #pragma unroll 1
  for (int ri = 0; ri < 4; ++ri){
    int r = 4*rt + w + 64*ri;          // p(r) = 16*rt + 4*w + ri
    int klocal = 4*w + ri;
    const c32* ir = img_t + ((size_t)pol*NR + r)*NC;
    const c32* wr = w_t  + ((size_t)(pol*NSEG+seg)*NR + r)*NC;
    const c32* cr = c_t  + ((size_t)cl*NR + r)*NC;
    c32 x[4];
    #pragma unroll
    for (int i = 0; i < 4; ++i){
      int c = u + 64*i;
      x[i] = cmul(cmul(ir[c], wr[c]), cr[c]);
    }
    fft256<1>(x, fbuf[w][0], fbuf[w][1], T, u);
    #pragma unroll
    for (int t = 0; t < 4; ++t)
      tile[(u + 64*t)*17 + klocal] = __floats2half2_rn(x[t].x, x[t].y);
  }
  __syncthreads();
  // copy: thread (a=tid>>2, m=tid&3); per k: cc = a + 64k; store 16B chunk
  int a = tid >> 2, m = tid & 3;
  #pragma unroll
  for (int k = 0; k < 4; ++k){
    int cc = a + 64*k;
    __half2 h0 = tile[cc*17 + 4*m + 0];
    __half2 h1 = tile[cc*17 + 4*m + 1];
    __half2 h2 = tile[cc*17 + 4*m + 2];
    __half2 h3 = tile[cc*17 + 4*m + 3];
    uint4 pk = make_uint4(*(unsigned*)&h0, *(unsigned*)&h1,
                          *(unsigned*)&h2, *(unsigned*)&h3);
    *(uint4*)(T1 + (size_t)p*(NR*NC) + (size_t)cc*NR + 16*rt + 4*m) = pk;
  }
}

// ---------------------------------------------------------------------------
// stage B: block owns cols {4ct+w+64j}; per col: fwd col-FFT per seg
// (b128 p-order loads), K = sum(mask*X); per seg': re-mask, inv col-FFT,
// transpose via [16][256] tile, write T2[p][r][p-order c] (64B lines).
// grid: CH*NPOL*16 blocks of 256.
__global__ __launch_bounds__(256) void stageB_kernel(
    const __half2* __restrict__ T1, const __half* __restrict__ m_t,
    __half2* __restrict__ T2)
{
  __shared__ c32 fbuf[4][2][272];
  __shared__ __half2 tile[16][256];
  int tid = threadIdx.x, u = tid & 63, w = tid >> 6;
  TW T; mk_tw(u, T);
  int bid = blockIdx.x;
  int ct = bid & 15;
  int g  = bid >> 4;           // cl*NPOL + pol
  int pol = g & 1;
  const size_t PL = (size_t)NR*NC;

  c32 K[4][4];
  #pragma unroll
  for (int j = 0; j < 4; ++j)
    #pragma unroll
    for (int t = 0; t < 4; ++t) K[j][t] = make_float2(0.f, 0.f);

  // phase 1: forward column FFTs, K = sum_seg mask*FFT(col)
  #pragma unroll 1
  for (int j = 0; j < 4; ++j){
    int col = 4*ct + w + 64*j;
    uint4 dj[4]; uint2 mj[4];
    #pragma unroll
    for (int seg = 0; seg < NSEG; ++seg){
      dj[seg] = *(const uint4*)(T1 + ((size_t)(g*NSEG+seg))*PL
                                + (size_t)col*NR + 4*u);
      mj[seg] = *(const uint2*)(m_t + ((size_t)(pol*NSEG+seg)*NC + col)*NR + 4*u);
    }
    #pragma unroll
    for (int seg = 0; seg < NSEG; ++seg){
      c32 x[4]; float mv[4];
      const __half2* hp = (const __half2*)&dj[seg];
      const __half*  mp = (const __half*)&mj[seg];
      #pragma unroll
      for (int i = 0; i < 4; ++i){
        x[i]  = __half22float2(hp[i]);
        mv[i] = __half2float(mp[i]);
      }
      fft256<1>(x, fbuf[w][0], fbuf[w][1], T, u);
      #pragma unroll
      for (int t = 0; t < 4; ++t){
        K[j][t].x += mv[t]*x[t].x;
        K[j][t].y += mv[t]*x[t].y;
      }
    }
  }
  // phase 2: per seg' re-mask, inverse col FFT, transpose, store T2
  #pragma unroll 1
  for (int seg = 0; seg < NSEG; ++seg){
    uint2 mj[4];
    #pragma unroll
    for (int j = 0; j < 4; ++j){
      int col = 4*ct + w + 64*j;
      mj[j] = *(const uint2*)(m_t + ((size_t)(pol*NSEG+seg)*NC + col)*NR + 4*u);
    }
    #pragma unroll
    for (int j = 0; j < 4; ++j){
      c32 x[4];
      const __half* mp = (const __half*)&mj[j];
      #pragma unroll
      for (int t = 0; t < 4; ++t){
        float mv = __half2float(mp[t]);
        x[t] = make_float2(K[j][t].x*mv, K[j][t].y*mv);
      }
      fft256<-1>(x, fbuf[w][0], fbuf[w][1], T, u);
      #pragma unroll
      for (int t = 0; t < 4; ++t)
        tile[4*w+j][u + 64*t] = __floats2half2_rn(x[t].x*(1.0f/256.0f),
                                                  x[t].y*(1.0f/256.0f));
    }
    __syncthreads();
    {
      int r = tid;
      unsigned pk[16];
      #pragma unroll
      for (int k = 0; k < 16; ++k){
        __half2 h = tile[k][r];
        pk[k] = *(unsigned*)&h;
      }
      uint4* dst = (uint4*)(T2 + ((size_t)(g*NSEG+seg))*PL
                            + (size_t)r*NC + 16*ct);
      dst[0] = make_uint4(pk[0],  pk[1],  pk[2],  pk[3]);
      dst[1] = make_uint4(pk[4],  pk[5],  pk[6],  pk[7]);
      dst[2] = make_uint4(pk[8],  pk[9],  pk[10], pk[11]);
      dst[3] = make_uint4(pk[12], pk[13], pk[14], pk[15]);
    }
    __syncthreads();
  }
}

// ---------------------------------------------------------------------------
// stage C: row inv-FFT from T2 (b128 p-order loads), * conj(w)*conj(csm),
// accumulate 2 coils x 4 segs, write fp16 partial.  No tile, no block syncs.
// grid: (CH/2)*NPOL*64 blocks of 256.
__global__ __launch_bounds__(256) void stageC_part_kernel(
    const __half2* __restrict__ T2, const c32* __restrict__ w_t,
    const c32* __restrict__ c_t, __half2* __restrict__ part, int ch0)
{
  __shared__ c32 fbuf[4][2][272];
  int tid = threadIdx.x, u = tid & 63, w = tid >> 6;
  TW T; mk_tw(u, T);
  int bid = blockIdx.x;
  int rq = bid & 63, pol = (bid>>6) & 1, ch = bid >> 7;
  int r = rq*4 + w;
  const size_t PL = (size_t)NR*NC;

  c32 acc[4];
  #pragma unroll
  for (int t = 0; t < 4; ++t) acc[t] = make_float2(0.f, 0.f);

  uint4 v = *(const uint4*)(T2 + ((size_t)((ch*2*NPOL+pol)*NSEG))*PL
                            + (size_t)r*NC + 4*u);
  #pragma unroll 1
  for (int pl = 0; pl < 2*NSEG; ++pl){
    int cl = ch*2 + (pl>>2), seg = pl & 3;
    c32 x[4];
    const __half2* hp = (const __half2*)&v;
    #pragma unroll
    for (int i = 0; i < 4; ++i) x[i] = __half22float2(hp[i]);
    if (pl < 2*NSEG-1){
      int cl2 = ch*2 + ((pl+1)>>2), seg2 = (pl+1) & 3;
      v = *(const uint4*)(T2 + ((size_t)((cl2*NPOL+pol)*NSEG+seg2))*PL
                          + (size_t)r*NC + 4*u);
    }
    // issue w/csm loads before the FFT so they fly under it
    const c32* wr = w_t + ((size_t)(pol*NSEG+seg)*NR + r)*NC;
    const c32* cr = c_t + ((size_t)cl*NR + r)*NC;
    c32 wv[4], cv[4];
    #pragma unroll
    for (int t = 0; t < 4; ++t){ wv[t] = wr[u + 64*t]; cv[t] = cr[u + 64*t]; }
    fft256<-1>(x, fbuf[w][0], fbuf[w][1], T, u);
    #pragma unroll
    for (int t = 0; t < 4; ++t){
      c32 vv = cmulj(x[t], wv[t]);
      vv = cmulj(vv, cv[t]);
      acc[t].x += vv.x;
      acc[t].y += vv.y;
    }
  }
  __half2* pp = part + ((size_t)((ch0+ch)*NPOL+pol))*PL + (size_t)r*NC;
  #pragma unroll
  for (int t = 0; t < 4; ++t)
    pp[u + 64*t] = __floats2half2_rn(acc[t].x, acc[t].y);
}

// reduceC: out interior = sign * sum over 16 chunks of partial.
// grid: NR blocks of 256 (thread = c, block = r)
__global__ __launch_bounds__(256) void reduceC_kernel(
    int b, const __half2* __restrict__ part, float* __restrict__ out)
{
  int r = blockIdx.x, c = threadIdx.x;
  const size_t PL = (size_t)NR*NC;
  float2 s[NPOL];
  #pragma unroll
  for (int pol = 0; pol < NPOL; ++pol) s[pol] = make_float2(0.f, 0.f);
  #pragma unroll 4
  for (int ch = 0; ch < NCC; ++ch){
    #pragma unroll
    for (int pol = 0; pol < NPOL; ++pol){
      float2 f = __half22float2(part[((size_t)(ch*NPOL+pol))*PL + (size_t)r*NC + c]);
      s[pol].x += f.x; s[pol].y += f.y;
    }
  }
  float sgn = ((r + c) & 1) ? -1.0f : 1.0f;
  float4 o = make_float4(sgn*s[0].x, sgn*s[0].y, sgn*s[1].x, sgn*s[1].y);
  size_t oidx = (((size_t)b*OD + (r+OFF))*OD + (c+OFF));   // float4 units
  ((float4*)out)[oidx] = o;
}

// ---------------------------------------------------------------------------
extern "C" void kernel_launch(void* const* d_in, const int* in_sizes, int n_in,
                              void* d_out, int out_size, void* d_ws, size_t ws_size,
                              hipStream_t stream)
{
  (void)in_sizes; (void)n_in;
  const float* x_re   = (const float*)d_in[0];
  const float* x_im   = (const float*)d_in[1];
  const float* csm_re = (const float*)d_in[2];
  const float* csm_im = (const float*)d_in[3];
  const float* wm_re  = (const float*)d_in[4];
  const float* wm_im  = (const float*)d_in[5];
  const float* mask   = (const float*)d_in[6];

  const size_t PL = (size_t)NR*NC;
  const size_t imgB1 = (size_t)NPOL*PL*sizeof(c32);           // 1 MiB / batch
  const size_t wB1   = (size_t)NPOL*NSEG*PL*sizeof(c32);      // 4 MiB / batch
  const size_t mB1   = (size_t)NPOL*NSEG*PL*sizeof(__half);   // 1 MiB / batch
  const size_t csmB1 = (size_t)NCOIL*PL*sizeof(c32);          // 16 MiB
  const size_t partB = (size_t)NCC*NPOL*PL*4;                 // 8 MiB fp16
  const size_t coilB = (size_t)NPOL*NSEG*PL*4;                // 2 MiB fp16 / coil

  const size_t fixed = NB*(imgB1 + wB1 + mB1) + csmB1 + partB; // 48 MiB

  int CH = 32;                       // T1+T2 = CH*4 MiB; CH=32 -> 176 MiB total
  while (CH > 4){
    if (fixed + (size_t)CH*2*coilB <= ws_size) break;
    CH >>= 1;
  }

  char* ws = (char*)d_ws;
  c32* img_t = (c32*)ws;
  c32* w_t   = (c32*)(ws + NB*imgB1);
  __half* m_t = (__half*)(ws + NB*(imgB1 + wB1));
  c32* c_t   = (c32*)(ws + NB*(imgB1 + wB1 + mB1));
  __half2* part = (__half2*)(ws + NB*(imgB1 + wB1 + mB1) + csmB1);
  __half2* T1 = (__half2*)(ws + fixed);
  __half2* T2 = (__half2*)(ws + fixed + (size_t)CH*coilB);

  float* out = (float*)d_out;
  zero_kernel<<<(out_size + 255)/256, 256, 0, stream>>>(out, out_size);

  pack_common_kernel<<<NB*NR, 256, 0, stream>>>(x_re, x_im, wm_re, wm_im,
                                                mask, img_t, w_t, m_t);
  for (int b = 0; b < NB; ++b){
    c32* img_b = img_t + (size_t)b*NPOL*PL;
    c32* w_b   = w_t   + (size_t)b*NPOL*NSEG*PL;
    __half* m_b = m_t  + (size_t)b*NPOL*NSEG*PL;
    pack_csm_kernel<<<NR, 256, 0, stream>>>(b, csm_re, csm_im, c_t);
    for (int c0 = 0; c0 < NCOIL; c0 += CH){
      c32* c_b = c_t + (size_t)c0*PL;
      stageA_kernel<<<CH*NPOL*NSEG*16, 256, 0, stream>>>(img_b, w_b, c_b, T1);
      stageB_kernel<<<CH*NPOL*16, 256, 0, stream>>>(T1, m_b, T2);
      stageC_part_kernel<<<(CH/2)*NPOL*64, 256, 0, stream>>>(T2, w_b, c_b,
                                                             part, c0/2);
    }
    reduceC_kernel<<<NR, 256, 0, stream>>>(b, part, out);
  }
}

// Round 9
// 607.670 us; speedup vs baseline: 1.2065x; 1.1317x over previous
//
#include <hip/hip_runtime.h>
#include <hip/hip_fp16.h>

#define NB 4
#define NR 256
#define NC 256
#define NCOIL 32
#define NSEG 4
#define NPOL 2
#define OD 276
#define OFF 10
#define NCC 16          // partial chunks = NCOIL/2 (2 coils per stageC block)

typedef float2 c32;

__device__ __forceinline__ c32 cmul(c32 a, c32 b){
  return make_float2(a.x*b.x - a.y*b.y, a.x*b.y + a.y*b.x);
}
__device__ __forceinline__ c32 cmulj(c32 a, c32 b){ // a * conj(b)
  return make_float2(a.x*b.x + a.y*b.y, a.y*b.x - a.x*b.y);
}
__device__ __forceinline__ int pd(int a){ return a + (a >> 4); }
__device__ __forceinline__ void wsync(){ __builtin_amdgcn_wave_barrier(); }

// Per-lane register twiddles for the 4 Stockham stages (replaces LDS table:
// exponent e1 = u & ~(m-1) is a per-lane constant per stage).
struct TW { c32 t1[4]; c32 t2[4]; c32 t3[4]; };
__device__ __forceinline__ void mk_tw(int u, TW& T){
  #pragma unroll
  for (int s = 0; s < 4; ++s){
    int e = u & ~((1 << (2*s)) - 1);
    float a = -0.0245436926061703f * (float)e;   // -2*pi*e/256
    float sn, cs; sincosf(a, &sn, &cs);
    c32 w1 = make_float2(cs, sn);                // W256^e (fwd sign)
    T.t1[s] = w1;
    T.t2[s] = cmul(w1, w1);
    T.t3[s] = cmul(T.t2[s], w1);
  }
}

// 256-pt radix-4 Stockham, one wave, 4 c32/lane, wave-private LDS b0/b1.
// In-place on x[4], natural order x[u+64*i].  DIR=+1 fwd, DIR=-1 unnorm inv.
// WAVE-SYNCHRONOUS (b0/b1 private to the calling wave).
template<int DIR>
__device__ __forceinline__ void fft256(c32* x, c32* b0, c32* b1,
                                       const TW& T, int u){
  #pragma unroll
  for (int s = 0; s < 4; ++s){
    const int m = 1 << (2*s);
    c32 a0, a1, a2, a3;
    if (s == 0){ a0 = x[0]; a1 = x[1]; a2 = x[2]; a3 = x[3]; }
    else {
      const c32* src = ((s & 1) ? b0 : b1);   // s=1:b0, s=2:b1, s=3:b0
      a0 = src[pd(u)]; a1 = src[pd(u+64)]; a2 = src[pd(u+128)]; a3 = src[pd(u+192)];
    }
    c32 s0 = make_float2(a0.x+a2.x, a0.y+a2.y);
    c32 d0 = make_float2(a0.x-a2.x, a0.y-a2.y);
    c32 s1 = make_float2(a1.x+a3.x, a1.y+a3.y);
    c32 d1 = make_float2(a1.x-a3.x, a1.y-a3.y);
    c32 X0 = make_float2(s0.x+s1.x, s0.y+s1.y);
    c32 X2 = make_float2(s0.x-s1.x, s0.y-s1.y);
    c32 X1, X3;
    if (DIR > 0){
      X1 = make_float2(d0.x + d1.y, d0.y - d1.x);  // d0 - i*d1
      X3 = make_float2(d0.x - d1.y, d0.y + d1.x);  // d0 + i*d1
    } else {
      X1 = make_float2(d0.x - d1.y, d0.y + d1.x);
      X3 = make_float2(d0.x + d1.y, d0.y - d1.x);
    }
    c32 w1 = T.t1[s], w2 = T.t2[s], w3 = T.t3[s];
    if (DIR < 0){ w1.y = -w1.y; w2.y = -w2.y; w3.y = -w3.y; }
    X1 = cmul(X1, w1); X2 = cmul(X2, w2); X3 = cmul(X3, w3);
    if (s == 3){
      x[0] = X0; x[1] = X1; x[2] = X2; x[3] = X3;
    } else {
      c32* dst = ((s & 1) ? b1 : b0);         // s=0:b0, s=1:b1, s=2:b0
      int j = u >> (2*s);
      int k = u & (m-1);
      int base = k + 4*m*j;
      dst[pd(base)]      = X0;
      dst[pd(base+m)]    = X1;
      dst[pd(base+2*m)]  = X2;
      dst[pd(base+3*m)]  = X3;
    }
    wsync();
  }
}

// ---------------------------------------------------------------------------
__global__ __launch_bounds__(256) void zero_kernel(float* __restrict__ out, int n){
  int i = blockIdx.x*256 + threadIdx.x;
  if (i < n) out[i] = 0.0f;
}

// ---------------------------------------------------------------------------
// pack_common: img_t[bl][pol][r][c] = crop(x)*(-1)^{r+c}/256 ;
// w_t[bl][pol*4+seg][r][c]; m_t[bl][pol*4+seg][c][r].
// grid: NB*NR blocks of 256 (thread = c)
__global__ __launch_bounds__(256) void pack_common_kernel(
    const float* __restrict__ x_re, const float* __restrict__ x_im,
    const float* __restrict__ wm_re, const float* __restrict__ wm_im,
    const float* __restrict__ mask,
    c32* __restrict__ img_t, c32* __restrict__ w_t, float* __restrict__ m_t)
{
  int r = blockIdx.x & (NR-1);
  int bl = blockIdx.x >> 8;
  int c = threadIdx.x;
  const size_t PL = (size_t)NR*NC;
  float sc = (((r + c) & 1) ? -1.0f : 1.0f) * (1.0f/256.0f);
  size_t xrow = (((size_t)bl*OD) + (r+OFF))*OD + (c+OFF);
  #pragma unroll
  for (int pol = 0; pol < NPOL; ++pol){
    size_t xi = xrow*NPOL + pol;
    img_t[((size_t)(bl*NPOL+pol))*PL + (size_t)r*NC + c] =
        make_float2(x_re[xi]*sc, x_im[xi]*sc);
  }
  size_t wbase = (((size_t)bl*NR + r)*NC + c)*(NPOL*NSEG);
  const float4* wre4 = (const float4*)&wm_re[wbase];
  const float4* wim4 = (const float4*)&wm_im[wbase];
  const float4* mk4  = (const float4*)&mask[wbase];
  #pragma unroll
  for (int pol = 0; pol < NPOL; ++pol){
    float4 re = wre4[pol], im = wim4[pol], mk = mk4[pol];
    float rr[4] = {re.x, re.y, re.z, re.w};
    float ii[4] = {im.x, im.y, im.z, im.w};
    float mm[4] = {mk.x, mk.y, mk.z, mk.w};
    #pragma unroll
    for (int seg = 0; seg < NSEG; ++seg){
      int ps = bl*(NPOL*NSEG) + pol*NSEG + seg;
      w_t[(size_t)ps*PL + (size_t)r*NC + c] = make_float2(rr[seg], ii[seg]);
      m_t[(size_t)ps*PL + (size_t)c*NR + r] = mm[seg];
    }
  }
}

// pack_csm: batch b, all coils: c_t[cl][r][c].  grid: NR blocks of 256
__global__ __launch_bounds__(256) void pack_csm_kernel(
    int b,
    const float* __restrict__ csm_re, const float* __restrict__ csm_im,
    c32* __restrict__ c_t)
{
  int r = blockIdx.x;
  int c = threadIdx.x;
  const size_t PL = (size_t)NR*NC;
  size_t base = (((size_t)b*NR + r)*NC + c)*NCOIL;
  c32* cp = c_t + (size_t)r*NC + c;
  for (int cl = 0; cl < NCOIL; cl += 4){
    float4 re = *(const float4*)&csm_re[base + cl];
    float4 im = *(const float4*)&csm_im[base + cl];
    cp[(size_t)(cl+0)*PL] = make_float2(re.x, im.x);
    cp[(size_t)(cl+1)*PL] = make_float2(re.y, im.y);
    cp[(size_t)(cl+2)*PL] = make_float2(re.z, im.z);
    cp[(size_t)(cl+3)*PL] = make_float2(re.w, im.w);
  }
}

// ---------------------------------------------------------------------------
// stage A: g = img*w*csm (scaled/signed already), row-FFT, write T1[p][c][r] fp16
// grid: CH*NPOL*NSEG*16 blocks of 256 (4 waves, 4 rows each)
__global__ __launch_bounds__(256) void stageA_kernel(
    const c32* __restrict__ img_t, const c32* __restrict__ w_t,
    const c32* __restrict__ c_t, __half2* __restrict__ T1)
{
  __shared__ c32 fbuf[4][2][272];
  __shared__ __half2 tile[NC*17];
  int tid = threadIdx.x;
  int u = tid & 63, w = tid >> 6;
  TW T; mk_tw(u, T);
  int bid = blockIdx.x;
  int p  = bid >> 4;           // ((cl*NPOL)+pol)*NSEG+seg
  int rt = bid & 15;
  int seg = p & 3, pol = (p>>2) & 1, cl = p >> 3;

  for (int ri = 0; ri < 4; ++ri){
    int rl = w*4 + ri;
    int r = rt*16 + rl;
    const c32* ir = img_t + ((size_t)pol*NR + r)*NC;
    const c32* wr = w_t  + ((size_t)(pol*NSEG+seg)*NR + r)*NC;
    const c32* cr = c_t  + ((size_t)cl*NR + r)*NC;
    c32 x[4];
    #pragma unroll
    for (int i = 0; i < 4; ++i){
      int c = u + 64*i;
      x[i] = cmul(cmul(ir[c], wr[c]), cr[c]);
    }
    fft256<1>(x, fbuf[w][0], fbuf[w][1], T, u);
    #pragma unroll
    for (int t = 0; t < 4; ++t){
      int c = u + 64*t;
      tile[c*17 + rl] = __floats2half2_rn(x[t].x, x[t].y);
    }
  }
  __syncthreads();
  __half2* tp = T1 + (size_t)p*(NR*NC);
  int r0 = rt*16;
  #pragma unroll
  for (int cb = 0; cb < 16; ++cb){
    int cc = w*64 + cb*4 + (u >> 4);
    int rl = u & 15;
    tp[cc*NR + r0 + rl] = tile[cc*17 + rl];
  }
}

// ---------------------------------------------------------------------------
// stage B: per column c: col-FFT per seg, K = sum(mask*X); then per seg':
// H = K*mask, col-iFFT, *(1/256), transpose via [16][256] LDS tile, write
// T2[p][r][c] fp16 ROW-MAJOR.  Each thread stores one FULL 64B row-segment.
// grid: CH*NPOL*16 blocks of 256 (4 waves, 4 columns per wave)
__global__ __launch_bounds__(256) void stageB_kernel(
    const __half2* __restrict__ T1, const float* __restrict__ m_t,
    __half2* __restrict__ T2)
{
  __shared__ c32 fbuf[4][2][272];
  __shared__ __half2 tile[16][256];
  int tid = threadIdx.x, u = tid & 63, w = tid >> 6;
  TW T; mk_tw(u, T);
  int bid = blockIdx.x;
  int ct = bid & 15;           // column panel
  int g  = bid >> 4;           // cl*NPOL + pol
  int pol = g & 1;
  int c0 = ct*16;
  const size_t PL = (size_t)NR*NC;

  c32 K[4][4];
  #pragma unroll
  for (int j = 0; j < 4; ++j)
    #pragma unroll
    for (int t = 0; t < 4; ++t) K[j][t] = make_float2(0.f, 0.f);

  // phase 1: forward column FFTs, K = sum_seg mask*FFT(col)
  #pragma unroll
  for (int j = 0; j < 4; ++j){
    int col = c0 + w*4 + j;
    #pragma unroll 1
    for (int seg = 0; seg < NSEG; ++seg){
      const __half2* tp = T1 + ((size_t)(g*NSEG+seg))*PL + (size_t)col*NR;
      const float*  mp = m_t + ((size_t)(pol*NSEG+seg))*PL + (size_t)col*NR;
      c32 x[4];
      float mv[4];
      #pragma unroll
      for (int i = 0; i < 4; ++i){
        x[i]  = __half22float2(tp[u + 64*i]);
        mv[i] = mp[u + 64*i];
      }
      fft256<1>(x, fbuf[w][0], fbuf[w][1], T, u);
      #pragma unroll
      for (int t = 0; t < 4; ++t){
        K[j][t].x += mv[t]*x[t].x;
        K[j][t].y += mv[t]*x[t].y;
      }
    }
  }
  // phase 2: per seg' re-mask, inverse col FFT, transpose, row-major store
  #pragma unroll 1
  for (int seg = 0; seg < NSEG; ++seg){
    #pragma unroll
    for (int j = 0; j < 4; ++j){
      int col = c0 + w*4 + j;
      const float* mp = m_t + ((size_t)(pol*NSEG+seg))*PL + (size_t)col*NR;
      c32 x[4];
      #pragma unroll
      for (int t = 0; t < 4; ++t){
        float mv = mp[u + 64*t];
        x[t] = make_float2(K[j][t].x*mv, K[j][t].y*mv);
      }
      fft256<-1>(x, fbuf[w][0], fbuf[w][1], T, u);
      #pragma unroll
      for (int t = 0; t < 4; ++t)
        tile[w*4+j][u + 64*t] = __floats2half2_rn(x[t].x*(1.0f/256.0f),
                                                  x[t].y*(1.0f/256.0f));
    }
    __syncthreads();
    {
      int r = tid;
      unsigned pk[16];
      #pragma unroll
      for (int k = 0; k < 16; ++k){
        __half2 h = tile[k][r];
        pk[k] = *(unsigned*)&h;
      }
      uint4* dst = (uint4*)(T2 + ((size_t)(g*NSEG+seg))*PL + (size_t)r*NC + c0);
      dst[0] = make_uint4(pk[0],  pk[1],  pk[2],  pk[3]);
      dst[1] = make_uint4(pk[4],  pk[5],  pk[6],  pk[7]);
      dst[2] = make_uint4(pk[8],  pk[9],  pk[10], pk[11]);
      dst[3] = make_uint4(pk[12], pk[13], pk[14], pk[15]);
    }
    __syncthreads();
  }
}

// ---------------------------------------------------------------------------
// stage C (partial): row-iFFT from ROW-MAJOR T2, * conj(w)*conj(csm),
// accumulate 2 coils x 4 segs, write fp16 partial[ch][pol][r][c].
// No LDS tile, no block barriers; next-plane + w/csm loads hoisted pre-FFT.
// grid: (CH/2)*NPOL*64 blocks of 256 (4 waves, 1 row each)
__global__ __launch_bounds__(256) void stageC_part_kernel(
    const __half2* __restrict__ T2, const c32* __restrict__ w_t,
    const c32* __restrict__ c_t, __half2* __restrict__ part, int ch0)
{
  __shared__ c32 fbuf[4][2][272];
  int tid = threadIdx.x, u = tid & 63, w = tid >> 6;
  TW T; mk_tw(u, T);
  int bid = blockIdx.x;
  int rq = bid & 63, pol = (bid>>6) & 1, ch = bid >> 7;   // local coil pair
  int r = rq*4 + w;
  const size_t PL = (size_t)NR*NC;

  c32 acc[4];
  #pragma unroll
  for (int t = 0; t < 4; ++t) acc[t] = make_float2(0.f, 0.f);

  __half2 v[4];
  {
    const __half2* rp = T2 + ((size_t)((ch*2*NPOL+pol)*NSEG))*PL + (size_t)r*NC;
    #pragma unroll
    for (int i = 0; i < 4; ++i) v[i] = rp[u + 64*i];
  }
  #pragma unroll 1
  for (int pl = 0; pl < 2*NSEG; ++pl){
    int cl = ch*2 + (pl>>2), seg = pl & 3;
    c32 x[4];
    #pragma unroll
    for (int i = 0; i < 4; ++i) x[i] = __half22float2(v[i]);
    if (pl < 2*NSEG-1){
      int cl2 = ch*2 + ((pl+1)>>2), seg2 = (pl+1) & 3;
      const __half2* rp = T2 + ((size_t)((cl2*NPOL+pol)*NSEG+seg2))*PL + (size_t)r*NC;
      #pragma unroll
      for (int i = 0; i < 4; ++i) v[i] = rp[u + 64*i];
    }
    // issue w/csm loads before the FFT so they fly under it
    const c32* wr = w_t + ((size_t)(pol*NSEG+seg)*NR + r)*NC;
    const c32* cr = c_t + ((size_t)cl*NR + r)*NC;
    c32 wv[4], cv[4];
    #pragma unroll
    for (int t = 0; t < 4; ++t){ wv[t] = wr[u + 64*t]; cv[t] = cr[u + 64*t]; }
    fft256<-1>(x, fbuf[w][0], fbuf[w][1], T, u);
    #pragma unroll
    for (int t = 0; t < 4; ++t){
      c32 vv = cmulj(x[t], wv[t]);
      vv = cmulj(vv, cv[t]);
      acc[t].x += vv.x;
      acc[t].y += vv.y;
    }
  }
  __half2* pp = part + ((size_t)((ch0+ch)*NPOL+pol))*PL + (size_t)r*NC;
  #pragma unroll
  for (int t = 0; t < 4; ++t)
    pp[u + 64*t] = __floats2half2_rn(acc[t].x, acc[t].y);
}

// reduceC: out interior = sign * sum over 16 chunks of partial. Plain stores.
// grid: NR blocks of 256 (thread = c, block = r)
__global__ __launch_bounds__(256) void reduceC_kernel(
    int b, const __half2* __restrict__ part, float* __restrict__ out)
{
  int r = blockIdx.x, c = threadIdx.x;
  const size_t PL = (size_t)NR*NC;
  float2 s[NPOL];
  #pragma unroll
  for (int pol = 0; pol < NPOL; ++pol) s[pol] = make_float2(0.f, 0.f);
  #pragma unroll 4
  for (int ch = 0; ch < NCC; ++ch){
    #pragma unroll
    for (int pol = 0; pol < NPOL; ++pol){
      float2 f = __half22float2(part[((size_t)(ch*NPOL+pol))*PL + (size_t)r*NC + c]);
      s[pol].x += f.x; s[pol].y += f.y;
    }
  }
  float sgn = ((r + c) & 1) ? -1.0f : 1.0f;
  float4 o = make_float4(sgn*s[0].x, sgn*s[0].y, sgn*s[1].x, sgn*s[1].y);
  size_t oidx = (((size_t)b*OD + (r+OFF))*OD + (c+OFF));   // float4 units
  ((float4*)out)[oidx] = o;
}

// ---------------------------------------------------------------------------
extern "C" void kernel_launch(void* const* d_in, const int* in_sizes, int n_in,
                              void* d_out, int out_size, void* d_ws, size_t ws_size,
                              hipStream_t stream)
{
  (void)in_sizes; (void)n_in;
  const float* x_re   = (const float*)d_in[0];
  const float* x_im   = (const float*)d_in[1];
  const float* csm_re = (const float*)d_in[2];
  const float* csm_im = (const float*)d_in[3];
  const float* wm_re  = (const float*)d_in[4];
  const float* wm_im  = (const float*)d_in[5];
  const float* mask   = (const float*)d_in[6];

  const size_t PL = (size_t)NR*NC;
  const size_t imgB1 = (size_t)NPOL*PL*sizeof(c32);           // 1 MiB / batch
  const size_t wB1   = (size_t)NPOL*NSEG*PL*sizeof(c32);      // 4 MiB / batch
  const size_t mB1   = (size_t)NPOL*NSEG*PL*sizeof(float);    // 2 MiB / batch
  const size_t csmB1 = (size_t)NCOIL*PL*sizeof(c32);          // 16 MiB
  const size_t partB = (size_t)NCC*NPOL*PL*4;                 // 8 MiB fp16
  const size_t coilB = (size_t)NPOL*NSEG*PL*4;                // 2 MiB fp16 / coil

  const size_t fixed = NB*(imgB1 + wB1 + mB1) + csmB1 + partB; // 52 MiB

  // coil chunk: T1 + T2 = CH * 4 MiB extra.
  int CH = 32;
  while (CH > 4){
    if (fixed + (size_t)CH*2*coilB <= ws_size) break;
    CH >>= 1;
  }

  char* ws = (char*)d_ws;
  c32* img_t = (c32*)ws;
  c32* w_t   = (c32*)(ws + NB*imgB1);
  float* m_t = (float*)(ws + NB*(imgB1 + wB1));
  c32* c_t   = (c32*)(ws + NB*(imgB1 + wB1 + mB1));
  __half2* part = (__half2*)(ws + NB*(imgB1 + wB1 + mB1) + csmB1);
  __half2* T1 = (__half2*)(ws + fixed);
  __half2* T2 = (__half2*)(ws + fixed + (size_t)CH*coilB);

  float* out = (float*)d_out;
  zero_kernel<<<(out_size + 255)/256, 256, 0, stream>>>(out, out_size);

  pack_common_kernel<<<NB*NR, 256, 0, stream>>>(x_re, x_im, wm_re, wm_im,
                                                mask, img_t, w_t, m_t);
  for (int b = 0; b < NB; ++b){
    c32* img_b = img_t + (size_t)b*NPOL*PL;
    c32* w_b   = w_t   + (size_t)b*NPOL*NSEG*PL;
    float* m_b = m_t   + (size_t)b*NPOL*NSEG*PL;
    pack_csm_kernel<<<NR, 256, 0, stream>>>(b, csm_re, csm_im, c_t);
    for (int c0 = 0; c0 < NCOIL; c0 += CH){
      c32* c_b = c_t + (size_t)c0*PL;
      stageA_kernel<<<CH*NPOL*NSEG*16, 256, 0, stream>>>(img_b, w_b, c_b, T1);
      stageB_kernel<<<CH*NPOL*16, 256, 0, stream>>>(T1, m_b, T2);
      stageC_part_kernel<<<(CH/2)*NPOL*64, 256, 0, stream>>>(T2, w_b, c_b,
                                                             part, c0/2);
    }
    reduceC_kernel<<<NR, 256, 0, stream>>>(b, part, out);
  }
}

// Round 10
// 584.523 us; speedup vs baseline: 1.2543x; 1.0396x over previous
//
#include <hip/hip_runtime.h>
#include <hip/hip_fp16.h>

#define NB 4
#define NR 256
#define NC 256
#define NCOIL 32
#define NSEG 4
#define NPOL 2
#define OD 276
#define OFF 10
#define NCC 16          // partial chunks = NCOIL/2 (2 coils per stageC block)

typedef float2 c32;

__device__ __forceinline__ c32 cmul(c32 a, c32 b){
  return make_float2(a.x*b.x - a.y*b.y, a.x*b.y + a.y*b.x);
}
__device__ __forceinline__ c32 cmulj(c32 a, c32 b){ // a * conj(b)
  return make_float2(a.x*b.x + a.y*b.y, a.y*b.x - a.x*b.y);
}
__device__ __forceinline__ c32 cmulc(c32 a, float br, float bi){
  return make_float2(a.x*br - a.y*bi, a.x*bi + a.y*br);
}
__device__ __forceinline__ void wsync(){ __builtin_amdgcn_wave_barrier(); }

#define C16A 0.9238795325112867f
#define S16A 0.3826834323650898f
#define RSQ2 0.7071067811865476f

// radix-4: out[c] = sum_a in[a] * W4^{a c}; W4 = -i fwd, +i inv
template<int DIR>
__device__ __forceinline__ void r4(c32 a0, c32 a1, c32 a2, c32 a3,
                                   c32& o0, c32& o1, c32& o2, c32& o3){
  c32 s0 = make_float2(a0.x+a2.x, a0.y+a2.y);
  c32 d0 = make_float2(a0.x-a2.x, a0.y-a2.y);
  c32 s1 = make_float2(a1.x+a3.x, a1.y+a3.y);
  c32 d1 = make_float2(a1.x-a3.x, a1.y-a3.y);
  o0 = make_float2(s0.x+s1.x, s0.y+s1.y);
  o2 = make_float2(s0.x-s1.x, s0.y-s1.y);
  if (DIR > 0){
    o1 = make_float2(d0.x + d1.y, d0.y - d1.x);  // d0 - i*d1
    o3 = make_float2(d0.x - d1.y, d0.y + d1.x);
  } else {
    o1 = make_float2(d0.x - d1.y, d0.y + d1.x);
    o3 = make_float2(d0.x + d1.y, d0.y - d1.x);
  }
}

// in-register 16-pt DFT: y[k] = sum_n y[n] W16^{DIR * n k}, fully unrolled
template<int DIR>
__device__ __forceinline__ void dft16(c32* y){
  const float sg = (DIR > 0) ? -1.0f : 1.0f;
  c32 g[16];
  #pragma unroll
  for (int b = 0; b < 4; ++b)
    r4<DIR>(y[b], y[b+4], y[b+8], y[b+12], g[b], g[4+b], g[8+b], g[12+b]);
  // g[4c+b] *= W16^{bc}
  g[5]  = cmulc(g[5],  C16A,  sg*S16A);   // W^1
  g[6]  = cmulc(g[6],  RSQ2,  sg*RSQ2);   // W^2
  g[7]  = cmulc(g[7],  S16A,  sg*C16A);   // W^3
  g[9]  = cmulc(g[9],  RSQ2,  sg*RSQ2);   // W^2
  g[10] = cmulc(g[10], 0.0f,  sg);        // W^4
  g[11] = cmulc(g[11], -RSQ2, sg*RSQ2);   // W^6
  g[13] = cmulc(g[13], S16A,  sg*C16A);   // W^3
  g[14] = cmulc(g[14], -RSQ2, sg*RSQ2);   // W^6
  g[15] = cmulc(g[15], -C16A, -sg*S16A);  // W^9
  #pragma unroll
  for (int c = 0; c < 4; ++c)
    r4<DIR>(g[4*c], g[4*c+1], g[4*c+2], g[4*c+3],
            y[c], y[c+4], y[c+8], y[c+12]);
}

// per-lane step-2 twiddle table: tw[r] = W256^{l*r} (W = e^{-2pi i/256})
__device__ __forceinline__ void mk_tw16(int l, c32* tw){
  float sn, cs;
  sincosf(-0.0245436926061703f * (float)l, &sn, &cs);
  c32 base = make_float2(cs, sn);
  tw[0] = make_float2(1.0f, 0.0f);
  #pragma unroll
  for (int r = 1; r < 16; ++r) tw[r] = cmul(tw[r-1], base);
}

// 256-pt FFT as 16x16: 4 FFTs per wave (one per 16-lane group g), lane l.
// Fwd:  in  T-layout  y[i] = x[16i+l]   -> out K-layout y[j] = X[l+16j]
// Inv:  in  K-layout  y[j] = X[l+16j]   -> out T-layout y[i] = x[16i+l] (unnorm)
// ONE LDS exchange (XOR-swizzled 16x16 transpose per group), scratch sc:
// 1024 c32 per wave.  Wave-synchronous.
template<int DIR>
__device__ __forceinline__ void fft256g(c32* y, const c32* tw, c32* sc,
                                        int l, int g){
  dft16<DIR>(y);
  #pragma unroll
  for (int r = 1; r < 16; ++r)
    y[r] = (DIR > 0) ? cmul(y[r], tw[r]) : cmulj(y[r], tw[r]);
  #pragma unroll
  for (int r = 0; r < 16; ++r)
    sc[((r*4 + g) << 4) + (l ^ r)] = y[r];
  wsync();
  #pragma unroll
  for (int j = 0; j < 16; ++j)
    y[j] = sc[((l*4 + g) << 4) + (j ^ l)];
  wsync();
  dft16<DIR>(y);
}

// ---------------------------------------------------------------------------
__global__ __launch_bounds__(256) void zero_kernel(float* __restrict__ out, int n){
  int i = blockIdx.x*256 + threadIdx.x;
  if (i < n) out[i] = 0.0f;
}

// ---------------------------------------------------------------------------
// pack_common: img_t[bl][pol][r][c] = crop(x)*(-1)^{r+c}/256 ;
// w_t[bl][pol*4+seg][r][c]; m_t[bl][pol*4+seg][c][r].
__global__ __launch_bounds__(256) void pack_common_kernel(
    const float* __restrict__ x_re, const float* __restrict__ x_im,
    const float* __restrict__ wm_re, const float* __restrict__ wm_im,
    const float* __restrict__ mask,
    c32* __restrict__ img_t, c32* __restrict__ w_t, float* __restrict__ m_t)
{
  int r = blockIdx.x & (NR-1);
  int bl = blockIdx.x >> 8;
  int c = threadIdx.x;
  const size_t PL = (size_t)NR*NC;
  float sc = (((r + c) & 1) ? -1.0f : 1.0f) * (1.0f/256.0f);
  size_t xrow = (((size_t)bl*OD) + (r+OFF))*OD + (c+OFF);
  #pragma unroll
  for (int pol = 0; pol < NPOL; ++pol){
    size_t xi = xrow*NPOL + pol;
    img_t[((size_t)(bl*NPOL+pol))*PL + (size_t)r*NC + c] =
        make_float2(x_re[xi]*sc, x_im[xi]*sc);
  }
  size_t wbase = (((size_t)bl*NR + r)*NC + c)*(NPOL*NSEG);
  const float4* wre4 = (const float4*)&wm_re[wbase];
  const float4* wim4 = (const float4*)&wm_im[wbase];
  const float4* mk4  = (const float4*)&mask[wbase];
  #pragma unroll
  for (int pol = 0; pol < NPOL; ++pol){
    float4 re = wre4[pol], im = wim4[pol], mk = mk4[pol];
    float rr[4] = {re.x, re.y, re.z, re.w};
    float ii[4] = {im.x, im.y, im.z, im.w};
    float mm[4] = {mk.x, mk.y, mk.z, mk.w};
    #pragma unroll
    for (int seg = 0; seg < NSEG; ++seg){
      int ps = bl*(NPOL*NSEG) + pol*NSEG + seg;
      w_t[(size_t)ps*PL + (size_t)r*NC + c] = make_float2(rr[seg], ii[seg]);
      m_t[(size_t)ps*PL + (size_t)c*NR + r] = mm[seg];
    }
  }
}

// pack_csm: batch b, all coils: c_t[cl][r][c].
__global__ __launch_bounds__(256) void pack_csm_kernel(
    int b,
    const float* __restrict__ csm_re, const float* __restrict__ csm_im,
    c32* __restrict__ c_t)
{
  int r = blockIdx.x;
  int c = threadIdx.x;
  const size_t PL = (size_t)NR*NC;
  size_t base = (((size_t)b*NR + r)*NC + c)*NCOIL;
  c32* cp = c_t + (size_t)r*NC + c;
  for (int cl = 0; cl < NCOIL; cl += 4){
    float4 re = *(const float4*)&csm_re[base + cl];
    float4 im = *(const float4*)&csm_im[base + cl];
    cp[(size_t)(cl+0)*PL] = make_float2(re.x, im.x);
    cp[(size_t)(cl+1)*PL] = make_float2(re.y, im.y);
    cp[(size_t)(cl+2)*PL] = make_float2(re.z, im.z);
    cp[(size_t)(cl+3)*PL] = make_float2(re.w, im.w);
  }
}

// ---------------------------------------------------------------------------
// stage A: row FFT of img*w*csm, write T1[p][k_c][r] fp16.
// Block: 16 rows (wave w, group g -> r = rt*16 + 4w + g), 4 FFTs per wave.
// grid: CH*NPOL*NSEG*16 blocks of 256
__global__ __launch_bounds__(256) void stageA_kernel(
    const c32* __restrict__ img_t, const c32* __restrict__ w_t,
    const c32* __restrict__ c_t, __half2* __restrict__ T1)
{
  __shared__ c32 fsc[4][1024];
  __shared__ __half2 tile[NC*20];    // [k_c][16 rows], pad 20
  int tid = threadIdx.x;
  int l = tid & 15, g = (tid >> 4) & 3, w = tid >> 6;
  c32 tw[16]; mk_tw16(l, tw);
  int bid = blockIdx.x;
  int p  = bid >> 4;                 // ((cl*NPOL)+pol)*NSEG+seg
  int rt = bid & 15;
  int seg = p & 3, pol = (p>>2) & 1, cl = p >> 3;
  int r = rt*16 + 4*w + g;

  const c32* ir = img_t + ((size_t)pol*NR + r)*NC;
  const c32* wr = w_t  + ((size_t)(pol*NSEG+seg)*NR + r)*NC;
  const c32* cr = c_t  + ((size_t)cl*NR + r)*NC;
  c32 y[16];
  #pragma unroll
  for (int i = 0; i < 16; ++i){
    int c = 16*i + l;
    y[i] = cmul(cmul(ir[c], wr[c]), cr[c]);
  }
  fft256g<1>(y, tw, fsc[w], l, g);
  int rl = 4*w + g;
  #pragma unroll
  for (int j = 0; j < 16; ++j)
    tile[(l + 16*j)*20 + rl] = __floats2half2_rn(y[j].x, y[j].y);
  __syncthreads();
  // copy out: thread = k_c, 16 consecutive rows -> 64B contiguous
  __half2* tp = T1 + (size_t)p*(NR*NC) + (size_t)tid*NR + rt*16;
  const __half2* trow = tile + tid*20;
  #pragma unroll
  for (int k = 0; k < 4; ++k){
    __half2 h0 = trow[4*k+0], h1 = trow[4*k+1];
    __half2 h2 = trow[4*k+2], h3 = trow[4*k+3];
    uint4 q = make_uint4(*(unsigned*)&h0, *(unsigned*)&h1,
                         *(unsigned*)&h2, *(unsigned*)&h3);
    *(uint4*)(tp + 4*k) = q;
  }
}

// ---------------------------------------------------------------------------
// stage B: col FFT per seg (T-layout loads), K = sum(mask*X) in K-layout;
// per seg': re-mask, inverse col FFT, transpose tile, write T2[p][r][k_c].
// Block: 16 cols (col = ct*16 + 4w + g).  grid: CH*NPOL*16 blocks of 256
__global__ __launch_bounds__(256) void stageB_kernel(
    const __half2* __restrict__ T1, const float* __restrict__ m_t,
    __half2* __restrict__ T2)
{
  __shared__ c32 fsc[4][1024];
  __shared__ __half2 tile[16*272];   // [col-local][r], pad 272
  int tid = threadIdx.x;
  int l = tid & 15, g = (tid >> 4) & 3, w = tid >> 6;
  c32 tw[16]; mk_tw16(l, tw);
  int bid = blockIdx.x;
  int ct = bid & 15;
  int gp = bid >> 4;                 // cl*NPOL + pol
  int pol = gp & 1;
  int col = ct*16 + 4*w + g;
  const size_t PL = (size_t)NR*NC;

  c32 K[16];
  #pragma unroll
  for (int j = 0; j < 16; ++j) K[j] = make_float2(0.f, 0.f);

  #pragma unroll 1
  for (int seg = 0; seg < NSEG; ++seg){
    const __half2* tp = T1 + ((size_t)(gp*NSEG+seg))*PL + (size_t)col*NR;
    const float*  mp = m_t + ((size_t)(pol*NSEG+seg)*NC + col)*NR;
    c32 y[16];
    #pragma unroll
    for (int i = 0; i < 16; ++i) y[i] = __half22float2(tp[16*i + l]);
    fft256g<1>(y, tw, fsc[w], l, g);
    #pragma unroll
    for (int j = 0; j < 16; ++j){
      float mv = mp[l + 16*j];
      K[j].x += mv*y[j].x;
      K[j].y += mv*y[j].y;
    }
  }
  #pragma unroll 1
  for (int seg = 0; seg < NSEG; ++seg){
    const float* mp = m_t + ((size_t)(pol*NSEG+seg)*NC + col)*NR;
    c32 y[16];
    #pragma unroll
    for (int j = 0; j < 16; ++j){
      float mv = mp[l + 16*j];
      y[j] = make_float2(K[j].x*mv, K[j].y*mv);
    }
    fft256g<-1>(y, tw, fsc[w], l, g);
    #pragma unroll
    for (int i = 0; i < 16; ++i)
      tile[(4*w+g)*272 + 16*i + l] = __floats2half2_rn(y[i].x*(1.0f/256.0f),
                                                       y[i].y*(1.0f/256.0f));
    __syncthreads();
    {
      unsigned pk[16];
      #pragma unroll
      for (int k = 0; k < 16; ++k){
        __half2 h = tile[k*272 + tid];
        pk[k] = *(unsigned*)&h;
      }
      uint4* dst = (uint4*)(T2 + ((size_t)(gp*NSEG+seg))*PL
                            + (size_t)tid*NC + ct*16);
      dst[0] = make_uint4(pk[0],  pk[1],  pk[2],  pk[3]);
      dst[1] = make_uint4(pk[4],  pk[5],  pk[6],  pk[7]);
      dst[2] = make_uint4(pk[8],  pk[9],  pk[10], pk[11]);
      dst[3] = make_uint4(pk[12], pk[13], pk[14], pk[15]);
    }
    __syncthreads();
  }
}

// ---------------------------------------------------------------------------
// stage C: row inverse FFT from T2 (K-layout loads), * conj(w)*conj(csm),
// accumulate 2 coils x 4 segs, write fp16 partial[ch][pol][r][c].
// Block: 16 rows (r = rt*16 + 4w + g).  grid: (CH/2)*NPOL*16 blocks of 256
__global__ __launch_bounds__(256) void stageC_part_kernel(
    const __half2* __restrict__ T2, const c32* __restrict__ w_t,
    const c32* __restrict__ c_t, __half2* __restrict__ part, int ch0)
{
  __shared__ c32 fsc[4][1024];
  int tid = threadIdx.x;
  int l = tid & 15, g = (tid >> 4) & 3, w = tid >> 6;
  c32 tw[16]; mk_tw16(l, tw);
  int bid = blockIdx.x;
  int rt = bid & 15, pol = (bid>>4) & 1, ch = bid >> 5;   // local coil pair
  int r = rt*16 + 4*w + g;
  const size_t PL = (size_t)NR*NC;

  c32 acc[16];
  #pragma unroll
  for (int i = 0; i < 16; ++i) acc[i] = make_float2(0.f, 0.f);

  #pragma unroll 1
  for (int pl = 0; pl < 2*NSEG; ++pl){
    int cl = ch*2 + (pl>>2), seg = pl & 3;
    const __half2* rp = T2 + ((size_t)((cl*NPOL+pol)*NSEG+seg))*PL
                        + (size_t)r*NC;
    c32 y[16];
    #pragma unroll
    for (int j = 0; j < 16; ++j) y[j] = __half22float2(rp[l + 16*j]);
    fft256g<-1>(y, tw, fsc[w], l, g);
    const c32* wr = w_t + ((size_t)(pol*NSEG+seg)*NR + r)*NC;
    const c32* cr = c_t + ((size_t)cl*NR + r)*NC;
    #pragma unroll
    for (int i = 0; i < 16; ++i){
      int c = 16*i + l;
      c32 vv = cmulj(y[i], wr[c]);
      vv = cmulj(vv, cr[c]);
      acc[i].x += vv.x;
      acc[i].y += vv.y;
    }
  }
  __half2* pp = part + ((size_t)((ch0+ch)*NPOL+pol))*PL + (size_t)r*NC;
  #pragma unroll
  for (int i = 0; i < 16; ++i)
    pp[16*i + l] = __floats2half2_rn(acc[i].x, acc[i].y);
}

// reduceC: out interior = sign * sum over 16 chunks of partial.
__global__ __launch_bounds__(256) void reduceC_kernel(
    int b, const __half2* __restrict__ part, float* __restrict__ out)
{
  int r = blockIdx.x, c = threadIdx.x;
  const size_t PL = (size_t)NR*NC;
  float2 s[NPOL];
  #pragma unroll
  for (int pol = 0; pol < NPOL; ++pol) s[pol] = make_float2(0.f, 0.f);
  #pragma unroll 4
  for (int ch = 0; ch < NCC; ++ch){
    #pragma unroll
    for (int pol = 0; pol < NPOL; ++pol){
      float2 f = __half22float2(part[((size_t)(ch*NPOL+pol))*PL + (size_t)r*NC + c]);
      s[pol].x += f.x; s[pol].y += f.y;
    }
  }
  float sgn = ((r + c) & 1) ? -1.0f : 1.0f;
  float4 o = make_float4(sgn*s[0].x, sgn*s[0].y, sgn*s[1].x, sgn*s[1].y);
  size_t oidx = (((size_t)b*OD + (r+OFF))*OD + (c+OFF));   // float4 units
  ((float4*)out)[oidx] = o;
}

// ---------------------------------------------------------------------------
extern "C" void kernel_launch(void* const* d_in, const int* in_sizes, int n_in,
                              void* d_out, int out_size, void* d_ws, size_t ws_size,
                              hipStream_t stream)
{
  (void)in_sizes; (void)n_in;
  const float* x_re   = (const float*)d_in[0];
  const float* x_im   = (const float*)d_in[1];
  const float* csm_re = (const float*)d_in[2];
  const float* csm_im = (const float*)d_in[3];
  const float* wm_re  = (const float*)d_in[4];
  const float* wm_im  = (const float*)d_in[5];
  const float* mask   = (const float*)d_in[6];

  const size_t PL = (size_t)NR*NC;
  const size_t imgB1 = (size_t)NPOL*PL*sizeof(c32);           // 1 MiB / batch
  const size_t wB1   = (size_t)NPOL*NSEG*PL*sizeof(c32);      // 4 MiB / batch
  const size_t mB1   = (size_t)NPOL*NSEG*PL*sizeof(float);    // 2 MiB / batch
  const size_t csmB1 = (size_t)NCOIL*PL*sizeof(c32);          // 16 MiB
  const size_t partB = (size_t)NCC*NPOL*PL*4;                 // 8 MiB fp16
  const size_t coilB = (size_t)NPOL*NSEG*PL*4;                // 2 MiB fp16 / coil

  const size_t fixed = NB*(imgB1 + wB1 + mB1) + csmB1 + partB; // 52 MiB

  int CH = 32;
  while (CH > 4){
    if (fixed + (size_t)CH*2*coilB <= ws_size) break;
    CH >>= 1;
  }

  char* ws = (char*)d_ws;
  c32* img_t = (c32*)ws;
  c32* w_t   = (c32*)(ws + NB*imgB1);
  float* m_t = (float*)(ws + NB*(imgB1 + wB1));
  c32* c_t   = (c32*)(ws + NB*(imgB1 + wB1 + mB1));
  __half2* part = (__half2*)(ws + NB*(imgB1 + wB1 + mB1) + csmB1);
  __half2* T1 = (__half2*)(ws + fixed);
  __half2* T2 = (__half2*)(ws + fixed + (size_t)CH*coilB);

  float* out = (float*)d_out;
  zero_kernel<<<(out_size + 255)/256, 256, 0, stream>>>(out, out_size);

  pack_common_kernel<<<NB*NR, 256, 0, stream>>>(x_re, x_im, wm_re, wm_im,
                                                mask, img_t, w_t, m_t);
  for (int b = 0; b < NB; ++b){
    c32* img_b = img_t + (size_t)b*NPOL*PL;
    c32* w_b   = w_t   + (size_t)b*NPOL*NSEG*PL;
    float* m_b = m_t   + (size_t)b*NPOL*NSEG*PL;
    pack_csm_kernel<<<NR, 256, 0, stream>>>(b, csm_re, csm_im, c_t);
    for (int c0 = 0; c0 < NCOIL; c0 += CH){
      c32* c_b = c_t + (size_t)c0*PL;
      stageA_kernel<<<CH*NPOL*NSEG*16, 256, 0, stream>>>(img_b, w_b, c_b, T1);
      stageB_kernel<<<CH*NPOL*16, 256, 0, stream>>>(T1, m_b, T2);
      stageC_part_kernel<<<(CH/2)*NPOL*16, 256, 0, stream>>>(T2, w_b, c_b,
                                                             part, c0/2);
    }
    reduceC_kernel<<<NR, 256, 0, stream>>>(b, part, out);
  }
}